// Round 2
// baseline (283.330 us; speedup 1.0000x reference)
//
#include <hip/hip_runtime.h>
#include <hip/hip_bf16.h>
#include <stdint.h>

// MHA: B=1, L=4096, D=1024, H=16, dk=64.
// Inputs fp32, OUTPUT fp32. Internal compute bf16 with fp32 accumulation.
//
// Flash v5: LDS-bandwidth attack.  v4 was LDS-pipe-bound (traffic floor
// 84us vs 98us measured): all 8 waves re-read the whole K/V chunk.
// v5 splits kv by parity across the two 4-wave groups (group g processes
// chunks 2*mc+g), halving K/V LDS reads per unit work.  Max-free exp2
// softmax makes the cross-group combine exactly additive (oT+=, ls+=).
// Pb is XOR-swizzled [16][64] (conflict-free, was ~4-way at stride 72).
// LDS = 32K Kpair + 32K Vpair + 16K Pb = 80 KB exactly -> 2 blocks/CU.

typedef __bf16 bf16_t;
typedef __bf16 bf16x8 __attribute__((ext_vector_type(8)));
typedef __bf16 bf16x4 __attribute__((ext_vector_type(4)));
typedef float f32x4 __attribute__((ext_vector_type(4)));
typedef unsigned short u16x8 __attribute__((ext_vector_type(8)));

#define MFMA_BF16 __builtin_amdgcn_mfma_f32_16x16x32_bf16

__device__ __forceinline__ void async_copy16(const void* g, void* lds) {
  __builtin_amdgcn_global_load_lds(
      (__attribute__((address_space(1))) void*)(uintptr_t)g,
      (__attribute__((address_space(3))) void*)lds, 16, 0, 0);
}

// ---------------------------------------------------------------------------
// fp32 -> bf16 cast, 8 elems/thread, z selects tensor.
// ---------------------------------------------------------------------------
__global__ __launch_bounds__(256) void cast_f32_bf16(
    const float* __restrict__ s0, bf16_t* __restrict__ d0, int n0,
    const float* __restrict__ s1, bf16_t* __restrict__ d1, int n1,
    const float* __restrict__ s2, bf16_t* __restrict__ d2, int n2,
    const float* __restrict__ s3, bf16_t* __restrict__ d3, int n3,
    const float* __restrict__ s4, bf16_t* __restrict__ d4, int n4,
    const float* __restrict__ s5, bf16_t* __restrict__ d5, int n5,
    const float* __restrict__ s6, bf16_t* __restrict__ d6, int n6) {
  const float* s;
  bf16_t* d;
  int n;
  switch (blockIdx.z) {
    case 0: s = s0; d = d0; n = n0; break;
    case 1: s = s1; d = d1; n = n1; break;
    case 2: s = s2; d = d2; n = n2; break;
    case 3: s = s3; d = d3; n = n3; break;
    case 4: s = s4; d = d4; n = n4; break;
    case 5: s = s5; d = d5; n = n5; break;
    default: s = s6; d = d6; n = n6; break;
  }
  const int i = (blockIdx.x * 256 + threadIdx.x) * 8;
  if (i >= n) return;
  float4 a = *(const float4*)(s + i);
  float4 b = *(const float4*)(s + i + 4);
  bf16x8 o;
  o[0] = (bf16_t)a.x; o[1] = (bf16_t)a.y; o[2] = (bf16_t)a.z; o[3] = (bf16_t)a.w;
  o[4] = (bf16_t)b.x; o[5] = (bf16_t)b.y; o[6] = (bf16_t)b.z; o[7] = (bf16_t)b.w;
  *(bf16x8*)(d + i) = o;
}

// ---------------------------------------------------------------------------
// GEMM: C = A @ W^T + b.  Tile 128x128, BK=32, 4 waves in 2x2 (m97 shape).
// ---------------------------------------------------------------------------
template <typename CT>
__global__ __launch_bounds__(256) void gemm3_bt(
    const bf16_t* __restrict__ A0, const bf16_t* __restrict__ W0,
    const float* __restrict__ b0, CT* __restrict__ C0,
    const bf16_t* __restrict__ A1, const bf16_t* __restrict__ W1,
    const float* __restrict__ b1, CT* __restrict__ C1,
    const bf16_t* __restrict__ A2, const bf16_t* __restrict__ W2,
    const float* __restrict__ b2, CT* __restrict__ C2,
    int M, int N, int K) {
  const bf16_t *A, *W;
  const float* bias;
  CT* C;
  if (blockIdx.z == 0)      { A = A0; W = W0; bias = b0; C = C0; }
  else if (blockIdx.z == 1) { A = A1; W = W1; bias = b1; C = C1; }
  else                      { A = A2; W = W2; bias = b2; C = C2; }

  __shared__ bf16_t As[128][32];
  __shared__ bf16_t Bs[128][32];

  const int t = threadIdx.x;
  const int w = t >> 6, lane = t & 63;
  const int quad = lane >> 4, l16 = lane & 15;
  const int wr = w >> 1, wc = w & 1;
  const int m0 = blockIdx.x * 128;
  const int n0 = blockIdx.y * 128;
  const int srow = lane >> 2;
  const int scol = (lane & 3) * 8;

  f32x4 acc[4][4] = {};

  for (int k0 = 0; k0 < K; k0 += 32) {
    async_copy16(&A[(size_t)(m0 + (2 * w) * 16 + srow) * K + k0 + scol],
                 (char*)As + (2 * w) * 1024);
    async_copy16(&A[(size_t)(m0 + (2 * w + 1) * 16 + srow) * K + k0 + scol],
                 (char*)As + (2 * w + 1) * 1024);
    async_copy16(&W[(size_t)(n0 + (2 * w) * 16 + srow) * K + k0 + scol],
                 (char*)Bs + (2 * w) * 1024);
    async_copy16(&W[(size_t)(n0 + (2 * w + 1) * 16 + srow) * K + k0 + scol],
                 (char*)Bs + (2 * w + 1) * 1024);
    __syncthreads();

    bf16x8 af[4], bfr[4];
#pragma unroll
    for (int mt = 0; mt < 4; mt++)
      af[mt] = *(const bf16x8*)&As[wr * 64 + mt * 16 + l16][quad * 8];
#pragma unroll
    for (int nt = 0; nt < 4; nt++)
      bfr[nt] = *(const bf16x8*)&Bs[wc * 64 + nt * 16 + l16][quad * 8];
#pragma unroll
    for (int mt = 0; mt < 4; mt++)
#pragma unroll
      for (int nt = 0; nt < 4; nt++)
        acc[mt][nt] = MFMA_BF16(af[mt], bfr[nt], acc[mt][nt], 0, 0, 0);
    __syncthreads();
  }

#pragma unroll
  for (int nt = 0; nt < 4; nt++) {
    const int col = n0 + wc * 64 + nt * 16 + l16;
    const float bb = bias[col];
#pragma unroll
    for (int mt = 0; mt < 4; mt++) {
#pragma unroll
      for (int r = 0; r < 4; r++) {
        const int row = m0 + wr * 64 + mt * 16 + quad * 4 + r;
        C[(size_t)row * N + col] = (CT)(acc[mt][nt][r] + bb);
      }
    }
  }
}

// ---------------------------------------------------------------------------
// Fragment-tiling transform (unchanged).  Per head, [4096][64] -> 256 tiles
// of 16x64 in MFMA operand order; granule (kc,quad,l16) so a frag load is
// one b128 at tilebase + kc*512 + lane*8 elems.  z=0 Q (scaled), z=1 K,
// z=2 V transposed (tile = 16 dk-rows x 64 kv).
// ---------------------------------------------------------------------------
__global__ __launch_bounds__(256) void frag_tile(
    const bf16_t* __restrict__ s0, bf16_t* __restrict__ d0,
    const bf16_t* __restrict__ s1, bf16_t* __restrict__ d1,
    const bf16_t* __restrict__ s2, bf16_t* __restrict__ d2) {
  const bf16_t* src;
  bf16_t* dst;
  const int z = blockIdx.z;
  if (z == 0)      { src = s0; dst = d0; }
  else if (z == 1) { src = s1; dst = d1; }
  else             { src = s2; dst = d2; }

  const int h = blockIdx.y;
  const int l0 = blockIdx.x * 64;
  const int t = threadIdx.x;

  __shared__ ushort Ts[64][72];

#pragma unroll
  for (int p = 0; p < 2; p++) {
    const int r = p * 32 + (t >> 3);
    const int c = (t & 7) * 8;
    float4 v = *(const float4*)(src + (size_t)(l0 + r) * 1024 + h * 64 + c);
    *(float4*)&Ts[r][c] = v;
  }
  __syncthreads();

  if (z < 2) {
    const float qscale = 0.125f * 1.44269504088896340736f;
#pragma unroll
    for (int p = 0; p < 2; p++) {
      const int gi = p * 256 + t;
      const int l16 = gi & 15, quad = (gi >> 4) & 3, kc = (gi >> 6) & 1;
      const int tl = gi >> 7;  // 0..3
      float4 v = *(const float4*)&Ts[tl * 16 + l16][kc * 32 + quad * 8];
      if (z == 0) {
        bf16x8 b = *(bf16x8*)&v;
#pragma unroll
        for (int e = 0; e < 8; e++) b[e] = (bf16_t)((float)b[e] * qscale);
        v = *(float4*)&b;
      }
      *(float4*)(dst + (size_t)(h * 256 + (l0 >> 4) + tl) * 1024 +
                 (size_t)(kc * 64 + quad * 16 + l16) * 8) = v;
    }
  } else {
#pragma unroll
    for (int p = 0; p < 2; p++) {
      const int gi = p * 256 + t;
      const int l16 = gi & 15, quad = (gi >> 4) & 3, kvc = (gi >> 6) & 1;
      const int dkt = gi >> 7;  // 0..3
      u16x8 tmp;
#pragma unroll
      for (int e = 0; e < 8; e++)
        tmp[e] = Ts[kvc * 32 + quad * 8 + e][dkt * 16 + l16];
      *(u16x8*)(dst + (size_t)(h * 256 + (l0 >> 6) * 4 + dkt) * 1024 +
                (size_t)(kvc * 64 + quad * 16 + l16) * 8) = tmp;
    }
  }
}

// ---------------------------------------------------------------------------
// Flash v5.  Block = 8 waves / 512 threads, one head, 64 q-rows:
// wave w -> q-tile tq = qblk*4 + (w&3), kv-parity g = w>>2.
// Macro-iter mc stages the chunk PAIR (2mc, 2mc+1) = 16 KB K + 16 KB V
// contiguous in frag-major layout (double-buffered global_load_lds, 4
// copies/thread).  Group g computes chunk 2mc+g only -> each K/V byte is
// read by 4 waves, not 8 (halves the dominant LDS-read term; v4 was
// LDS-pipe-bound).  Max-free exp2 softmax => cross-group combine is a pure
// add of (oT, ls) at the end via LDS scratch.
// Pb: [16][64] bf16 rows with 16B XOR swizzle (byte ^= (l16&7)<<4) on both
// write and read -> conflict-free (stride-72 pad was ~4-way).
// LDS: 32K + 32K + 16K = 80 KB exactly -> 2 blocks/CU, 16 waves/CU.
// Flat grid 1024, bijective head->XCD remap (2 heads per XCD).
// ---------------------------------------------------------------------------
__global__ __launch_bounds__(512, 4) void flash_attn(
    const bf16_t* __restrict__ Qt, const bf16_t* __restrict__ Kt,
    const bf16_t* __restrict__ Vt, bf16_t* __restrict__ O, int L) {
  // linear block id i lands on XCD i%8 (round-robin dispatch).
  const int i = blockIdx.x;
  const int slot = i >> 3;               // 0..127 within XCD
  const int h = (i & 7) * 2 + (slot >> 6);  // 2 heads per XCD
  const int qblk = slot & 63;

  const int t = threadIdx.x;
  const int w = t >> 6, lane = t & 63;
  const int quad = lane >> 4, l16 = lane & 15;
  const int g = w >> 2;        // kv parity group
  const int ws = w & 3;        // q-tile sub-index within group
  const int tq = qblk * 4 + ws;

  __shared__ bf16_t Kst[2][8192];   // 16 KB per buffer (chunk pair)
  __shared__ bf16_t Vst[2][8192];   // 16 KB per buffer
  __shared__ bf16_t Pb[8][16][64];  // per-wave P, XOR-swizzled, 16 KB

  const size_t hb = (size_t)h * 256 * 1024;  // head base in tiled layouts

  // persistent Q B-frags (one q-tile per wave)
  bf16x8 qa[2];
#pragma unroll
  for (int kc = 0; kc < 2; kc++)
    qa[kc] = *(const bf16x8*)(Qt + hb + (size_t)tq * 1024 + kc * 512 +
                              lane * 8);

  // stage chunk pair `mc` (chunks 2mc, 2mc+1): 16 KB K + 16 KB V contiguous.
#define STAGE(mc_, buf_)                                                      \
  {                                                                           \
    const size_t pb_ = hb + (size_t)(mc_) * 8192;                             \
    async_copy16(Kt + pb_ + (size_t)t * 8, (char*)&Kst[buf_][0] + w * 1024);  \
    async_copy16(Kt + pb_ + 4096 + (size_t)t * 8,                             \
                 (char*)&Kst[buf_][0] + 8192 + w * 1024);                     \
    async_copy16(Vt + pb_ + (size_t)t * 8, (char*)&Vst[buf_][0] + w * 1024);  \
    async_copy16(Vt + pb_ + 4096 + (size_t)t * 8,                             \
                 (char*)&Vst[buf_][0] + 8192 + w * 1024);                     \
  }

  STAGE(0, 0);

  f32x4 oT[4] = {};  // [dkt]
  float ls = 0.f;
  const int swz = (l16 & 7) << 4;
  char* prow = (char*)&Pb[w][l16][0];

  const int NMC = L / 128;  // 32 macro-iters, 2 chunks each
  for (int mc = 0; mc < NMC; mc++) {
    const int buf = mc & 1;
    __syncthreads();  // drains last macro-iter's copies; protects dbuf WAR
    if (mc + 1 < NMC) STAGE(mc + 1, buf ^ 1);

    const char* Kc = (const char*)&Kst[buf][0] + g * 8192;
    const char* Vc = (const char*)&Vst[buf][0] + g * 8192;

    // frag reads from staged LDS (conflict-free b128)
    bf16x8 kb[4][2], vb[4][2];
#pragma unroll
    for (int tt = 0; tt < 4; tt++)
#pragma unroll
      for (int kc = 0; kc < 2; kc++)
        kb[tt][kc] =
            *(const bf16x8*)(Kc + tt * 2048 + kc * 1024 + lane * 16);
#pragma unroll
    for (int dkt = 0; dkt < 4; dkt++)
#pragma unroll
      for (int kvc = 0; kvc < 2; kvc++)
        vb[dkt][kvc] =
            *(const bf16x8*)(Vc + dkt * 2048 + kvc * 1024 + lane * 16);

    // S^T tile: lane = (q=l16, kv=quad*4+r+16tt)
    f32x4 sT[4];
#pragma unroll
    for (int tt = 0; tt < 4; tt++) {
      f32x4 z = {0.f, 0.f, 0.f, 0.f};
      z = MFMA_BF16(kb[tt][0], qa[0], z, 0, 0, 0);
      z = MFMA_BF16(kb[tt][1], qa[1], z, 0, 0, 0);
      sT[tt] = z;
    }
    // p = 2^s ; lsum ; pack 4 kv-consecutive bf16 -> one b64 LDS write
#pragma unroll
    for (int tt = 0; tt < 4; tt++) {
      bf16x4 pk;
      float rs = 0.f;
#pragma unroll
      for (int r = 0; r < 4; r++) {
        const float p = __builtin_amdgcn_exp2f(sT[tt][r]);
        rs += p;
        pk[r] = (bf16_t)p;
      }
      ls += rs;
      *(bf16x4*)(prow + ((tt * 32 + quad * 8) ^ swz)) = pk;
    }

    // O^T += V^T . P  (wave-local LDS, in-order => no extra barrier)
    const bf16x8 pf0 = *(const bf16x8*)(prow + ((quad * 16) ^ swz));
    const bf16x8 pf1 = *(const bf16x8*)(prow + ((64 + quad * 16) ^ swz));
#pragma unroll
    for (int dkt = 0; dkt < 4; dkt++) {
      oT[dkt] = MFMA_BF16(vb[dkt][0], pf0, oT[dkt], 0, 0, 0);
      oT[dkt] = MFMA_BF16(vb[dkt][1], pf1, oT[dkt], 0, 0, 0);
    }
  }
#undef STAGE

  // cross-group combine: waves (ws,g=1) hand their partial (oT, ls) to the
  // matching (ws,g=0) wave via LDS scratch (reuses Kst; 20.5 KB < 32 KB).
  __syncthreads();
  float* scratch = (float*)&Kst[0][0];
  if (g == 1) {
    float* s = scratch + (size_t)(ws * 64 + lane) * 20;
#pragma unroll
    for (int dkt = 0; dkt < 4; dkt++) *(f32x4*)(s + dkt * 4) = oT[dkt];
    s[16] = ls;
  }
  __syncthreads();
  if (g == 0) {
    const float* s = scratch + (size_t)(ws * 64 + lane) * 20;
#pragma unroll
    for (int dkt = 0; dkt < 4; dkt++) oT[dkt] += *(const f32x4*)(s + dkt * 4);
    ls += s[16];

    // reduce ls across the 4 quads sharing each q-row; store O
    float l = ls;
    l += __shfl_xor(l, 16);
    l += __shfl_xor(l, 32);
    const float inv = 1.0f / l;
    const size_t row = (size_t)tq * 16 + l16;
#pragma unroll
    for (int dkt = 0; dkt < 4; dkt++)
#pragma unroll
      for (int r = 0; r < 4; r++)
        O[row * 1024 + h * 64 + dkt * 16 + quad * 4 + r] =
            (bf16_t)(oT[dkt][r] * inv);
  }
}

// ---------------------------------------------------------------------------
extern "C" void kernel_launch(void* const* d_in, const int* in_sizes, int n_in,
                              void* d_out, int out_size, void* d_ws,
                              size_t ws_size, hipStream_t stream) {
  const float* q  = (const float*)d_in[0];
  const float* k  = (const float*)d_in[1];
  const float* v  = (const float*)d_in[2];
  const float* wq = (const float*)d_in[3];
  const float* bq = (const float*)d_in[4];
  const float* wk = (const float*)d_in[5];
  const float* bk = (const float*)d_in[6];
  const float* wv = (const float*)d_in[7];
  const float* bv = (const float*)d_in[8];
  const float* wo = (const float*)d_in[9];
  const float* bo = (const float*)d_in[10];
  float* out = (float*)d_out;

  const int L = 4096, D = 1024;
  const int nLD = L * D;  // 4M
  const int nDD = D * D;  // 1M
  bf16_t* p = (bf16_t*)d_ws;
  bf16_t* qb  = p; p += nLD;
  bf16_t* kb  = p; p += nLD;
  bf16_t* vb  = p; p += nLD;
  bf16_t* wqb = p; p += nDD;
  bf16_t* wkb = p; p += nDD;
  bf16_t* wvb = p; p += nDD;
  bf16_t* wob = p; p += nDD;
  bf16_t* Qp  = p; p += nLD;
  bf16_t* Kp  = p; p += nLD;
  bf16_t* Vp  = p; p += nLD;
  bf16_t* Qt  = p; p += nLD;
  bf16_t* Kt  = p; p += nLD;
  bf16_t* Vt  = p; p += nLD;
  bf16_t* Op  = Qp;  // reuse: frag_tile consumed Qp before flash writes Op

  dim3 blk(256);
  cast_f32_bf16<<<dim3(nLD / (256 * 8), 1, 7), blk, 0, stream>>>(
      q, qb, nLD, k, kb, nLD, v, vb, nLD, wq, wqb, nDD, wk, wkb, nDD,
      wv, wvb, nDD, wo, wob, nDD);
  gemm3_bt<bf16_t><<<dim3(L / 128, D / 128, 3), blk, 0, stream>>>(
      qb, wqb, bq, Qp, kb, wkb, bk, Kp, vb, wvb, bv, Vp, L, D, D);
  frag_tile<<<dim3(L / 64, 16, 3), blk, 0, stream>>>(Qp, Qt, Kp, Kt, Vp, Vt);
  flash_attn<<<dim3((L / 64) * 16), dim3(512), 0, stream>>>(Qt, Kt, Vt, Op, L);
  gemm3_bt<float><<<dim3(L / 128, D / 128, 1), blk, 0, stream>>>(
      Op, wob, bo, out, Op, wob, bo, out, Op, wob, bo, out, L, D, D);
}

// Round 3
// 260.279 us; speedup vs baseline: 1.0886x; 1.0886x over previous
//
#include <hip/hip_runtime.h>
#include <hip/hip_bf16.h>
#include <stdint.h>

// MHA: B=1, L=4096, D=1024, H=16, dk=64.
// Inputs fp32, OUTPUT fp32. Internal compute bf16 with fp32 accumulation.
//
// Flash v6: LDS-volume attack, done right this time.
//  - Nq=2 q-tiles per wave: K/V frag reads amortize over 32 q-rows (the
//    dominant LDS term halves; v5's kv-split alone didn't change bytes/row).
//  - kv parity split across the two 4-wave groups restores 16 waves/CU.
//  - P never touches LDS: MFMA sums over k in any order as long as A and B
//    agree on the slot mapping, so V^T is READ (2x ds_read_b64 per frag) in
//    the kv order that S^T's register packets already have.  The entire P
//    write/read round-trip (and its bank conflicts) is deleted at zero
//    shuffle cost.
//  - LDS = 2x16K Kpair + 2x16K Vpair = 64 KB -> 2 blocks/CU.
//    __launch_bounds__(512,4) caps VGPR at 128 for 4 waves/SIMD.

typedef __bf16 bf16_t;
typedef __bf16 bf16x8 __attribute__((ext_vector_type(8)));
typedef __bf16 bf16x4 __attribute__((ext_vector_type(4)));
typedef float f32x4 __attribute__((ext_vector_type(4)));
typedef unsigned short u16x8 __attribute__((ext_vector_type(8)));

#define MFMA_BF16 __builtin_amdgcn_mfma_f32_16x16x32_bf16

__device__ __forceinline__ void async_copy16(const void* g, void* lds) {
  __builtin_amdgcn_global_load_lds(
      (__attribute__((address_space(1))) void*)(uintptr_t)g,
      (__attribute__((address_space(3))) void*)lds, 16, 0, 0);
}

// ---------------------------------------------------------------------------
// fp32 -> bf16 cast, 8 elems/thread, z selects tensor.
// ---------------------------------------------------------------------------
__global__ __launch_bounds__(256) void cast_f32_bf16(
    const float* __restrict__ s0, bf16_t* __restrict__ d0, int n0,
    const float* __restrict__ s1, bf16_t* __restrict__ d1, int n1,
    const float* __restrict__ s2, bf16_t* __restrict__ d2, int n2,
    const float* __restrict__ s3, bf16_t* __restrict__ d3, int n3,
    const float* __restrict__ s4, bf16_t* __restrict__ d4, int n4,
    const float* __restrict__ s5, bf16_t* __restrict__ d5, int n5,
    const float* __restrict__ s6, bf16_t* __restrict__ d6, int n6) {
  const float* s;
  bf16_t* d;
  int n;
  switch (blockIdx.z) {
    case 0: s = s0; d = d0; n = n0; break;
    case 1: s = s1; d = d1; n = n1; break;
    case 2: s = s2; d = d2; n = n2; break;
    case 3: s = s3; d = d3; n = n3; break;
    case 4: s = s4; d = d4; n = n4; break;
    case 5: s = s5; d = d5; n = n5; break;
    default: s = s6; d = d6; n = n6; break;
  }
  const int i = (blockIdx.x * 256 + threadIdx.x) * 8;
  if (i >= n) return;
  float4 a = *(const float4*)(s + i);
  float4 b = *(const float4*)(s + i + 4);
  bf16x8 o;
  o[0] = (bf16_t)a.x; o[1] = (bf16_t)a.y; o[2] = (bf16_t)a.z; o[3] = (bf16_t)a.w;
  o[4] = (bf16_t)b.x; o[5] = (bf16_t)b.y; o[6] = (bf16_t)b.z; o[7] = (bf16_t)b.w;
  *(bf16x8*)(d + i) = o;
}

// ---------------------------------------------------------------------------
// GEMM: C = A @ W^T + b.  Tile 128x128, BK=32, 4 waves in 2x2 (m97 shape).
// ---------------------------------------------------------------------------
template <typename CT>
__global__ __launch_bounds__(256) void gemm3_bt(
    const bf16_t* __restrict__ A0, const bf16_t* __restrict__ W0,
    const float* __restrict__ b0, CT* __restrict__ C0,
    const bf16_t* __restrict__ A1, const bf16_t* __restrict__ W1,
    const float* __restrict__ b1, CT* __restrict__ C1,
    const bf16_t* __restrict__ A2, const bf16_t* __restrict__ W2,
    const float* __restrict__ b2, CT* __restrict__ C2,
    int M, int N, int K) {
  const bf16_t *A, *W;
  const float* bias;
  CT* C;
  if (blockIdx.z == 0)      { A = A0; W = W0; bias = b0; C = C0; }
  else if (blockIdx.z == 1) { A = A1; W = W1; bias = b1; C = C1; }
  else                      { A = A2; W = W2; bias = b2; C = C2; }

  __shared__ bf16_t As[128][32];
  __shared__ bf16_t Bs[128][32];

  const int t = threadIdx.x;
  const int w = t >> 6, lane = t & 63;
  const int quad = lane >> 4, l16 = lane & 15;
  const int wr = w >> 1, wc = w & 1;
  const int m0 = blockIdx.x * 128;
  const int n0 = blockIdx.y * 128;
  const int srow = lane >> 2;
  const int scol = (lane & 3) * 8;

  f32x4 acc[4][4] = {};

  for (int k0 = 0; k0 < K; k0 += 32) {
    async_copy16(&A[(size_t)(m0 + (2 * w) * 16 + srow) * K + k0 + scol],
                 (char*)As + (2 * w) * 1024);
    async_copy16(&A[(size_t)(m0 + (2 * w + 1) * 16 + srow) * K + k0 + scol],
                 (char*)As + (2 * w + 1) * 1024);
    async_copy16(&W[(size_t)(n0 + (2 * w) * 16 + srow) * K + k0 + scol],
                 (char*)Bs + (2 * w) * 1024);
    async_copy16(&W[(size_t)(n0 + (2 * w + 1) * 16 + srow) * K + k0 + scol],
                 (char*)Bs + (2 * w + 1) * 1024);
    __syncthreads();

    bf16x8 af[4], bfr[4];
#pragma unroll
    for (int mt = 0; mt < 4; mt++)
      af[mt] = *(const bf16x8*)&As[wr * 64 + mt * 16 + l16][quad * 8];
#pragma unroll
    for (int nt = 0; nt < 4; nt++)
      bfr[nt] = *(const bf16x8*)&Bs[wc * 64 + nt * 16 + l16][quad * 8];
#pragma unroll
    for (int mt = 0; mt < 4; mt++)
#pragma unroll
      for (int nt = 0; nt < 4; nt++)
        acc[mt][nt] = MFMA_BF16(af[mt], bfr[nt], acc[mt][nt], 0, 0, 0);
    __syncthreads();
  }

#pragma unroll
  for (int nt = 0; nt < 4; nt++) {
    const int col = n0 + wc * 64 + nt * 16 + l16;
    const float bb = bias[col];
#pragma unroll
    for (int mt = 0; mt < 4; mt++) {
#pragma unroll
      for (int r = 0; r < 4; r++) {
        const int row = m0 + wr * 64 + mt * 16 + quad * 4 + r;
        C[(size_t)row * N + col] = (CT)(acc[mt][nt][r] + bb);
      }
    }
  }
}

// ---------------------------------------------------------------------------
// Fragment-tiling transform (unchanged).  Per head, [4096][64] -> 256 tiles
// of 16x64 in MFMA operand order; granule (kc,quad,l16) so a frag load is
// one b128 at tilebase + kc*512 + lane*8 elems.  z=0 Q (scaled), z=1 K,
// z=2 V transposed (tile = 16 dk-rows x 64 kv).
// ---------------------------------------------------------------------------
__global__ __launch_bounds__(256) void frag_tile(
    const bf16_t* __restrict__ s0, bf16_t* __restrict__ d0,
    const bf16_t* __restrict__ s1, bf16_t* __restrict__ d1,
    const bf16_t* __restrict__ s2, bf16_t* __restrict__ d2) {
  const bf16_t* src;
  bf16_t* dst;
  const int z = blockIdx.z;
  if (z == 0)      { src = s0; dst = d0; }
  else if (z == 1) { src = s1; dst = d1; }
  else             { src = s2; dst = d2; }

  const int h = blockIdx.y;
  const int l0 = blockIdx.x * 64;
  const int t = threadIdx.x;

  __shared__ ushort Ts[64][72];

#pragma unroll
  for (int p = 0; p < 2; p++) {
    const int r = p * 32 + (t >> 3);
    const int c = (t & 7) * 8;
    float4 v = *(const float4*)(src + (size_t)(l0 + r) * 1024 + h * 64 + c);
    *(float4*)&Ts[r][c] = v;
  }
  __syncthreads();

  if (z < 2) {
    const float qscale = 0.125f * 1.44269504088896340736f;
#pragma unroll
    for (int p = 0; p < 2; p++) {
      const int gi = p * 256 + t;
      const int l16 = gi & 15, quad = (gi >> 4) & 3, kc = (gi >> 6) & 1;
      const int tl = gi >> 7;  // 0..3
      float4 v = *(const float4*)&Ts[tl * 16 + l16][kc * 32 + quad * 8];
      if (z == 0) {
        bf16x8 b = *(bf16x8*)&v;
#pragma unroll
        for (int e = 0; e < 8; e++) b[e] = (bf16_t)((float)b[e] * qscale);
        v = *(float4*)&b;
      }
      *(float4*)(dst + (size_t)(h * 256 + (l0 >> 4) + tl) * 1024 +
                 (size_t)(kc * 64 + quad * 16 + l16) * 8) = v;
    }
  } else {
#pragma unroll
    for (int p = 0; p < 2; p++) {
      const int gi = p * 256 + t;
      const int l16 = gi & 15, quad = (gi >> 4) & 3, kvc = (gi >> 6) & 1;
      const int dkt = gi >> 7;  // 0..3
      u16x8 tmp;
#pragma unroll
      for (int e = 0; e < 8; e++)
        tmp[e] = Ts[kvc * 32 + quad * 8 + e][dkt * 16 + l16];
      *(u16x8*)(dst + (size_t)(h * 256 + (l0 >> 6) * 4 + dkt) * 1024 +
                (size_t)(kvc * 64 + quad * 16 + l16) * 8) = tmp;
    }
  }
}

// ---------------------------------------------------------------------------
// Flash v6.  Block = 8 waves / 512 threads, one head, 128 q-rows:
// wave (g = w>>2, ws = w&3) owns q-tiles tq0 = qblk*8 + ws*2 (+0,+1) and
// kv parity g.  Macro-iter mc stages chunk pair (2mc, 2mc+1): 16 KB K +
// 16 KB V (double-buffered global_load_lds, 4 copies/thread); group g
// computes chunk 2mc+g for BOTH its q-tiles -> K/V LDS reads amortize over
// 32 q-rows (half of v4).  P stays in registers: the PV MFMA's k-slots are
// relabeled to S^T's native packet order (kv = quad*4+r+16*tt), and V^T is
// read with two ds_read_b64 per fragment at the matching kv slots.  Same
// bytes, zero shuffles, no P LDS round-trip.
// Cross-group combine (exp2 max-free softmax => pure add) via LDS scratch.
// LDS 64 KB -> 2 blocks/CU; VGPR capped 128 -> 16 waves/CU (4/SIMD).
// ---------------------------------------------------------------------------
__global__ __launch_bounds__(512, 4) void flash_attn(
    const bf16_t* __restrict__ Qt, const bf16_t* __restrict__ Kt,
    const bf16_t* __restrict__ Vt, bf16_t* __restrict__ O, int L) {
  // linear block id lands on XCD i%8 (round-robin dispatch): 2 heads/XCD.
  const int i = blockIdx.x;
  const int slot = i >> 3;                  // 0..63 within XCD
  const int h = (i & 7) * 2 + (slot >> 5);  // 2 heads per XCD
  const int qblk = slot & 31;

  const int t = threadIdx.x;
  const int w = t >> 6, lane = t & 63;
  const int quad = lane >> 4, l16 = lane & 15;
  const int g = w >> 2;   // kv parity group
  const int ws = w & 3;   // q-pair index within group
  const int tq0 = qblk * 8 + ws * 2;

  __shared__ bf16_t Kst[2][8192];  // 16 KB per buffer (chunk pair)
  __shared__ bf16_t Vst[2][8192];  // 16 KB per buffer

  const size_t hb = (size_t)h * 256 * 1024;  // head base in tiled layouts

  union V8 {
    bf16x8 v8;
    bf16x4 v4[2];
  };

  // persistent Q B-frags (two q-tiles per wave)
  bf16x8 qa[2][2];
#pragma unroll
  for (int qt = 0; qt < 2; qt++)
#pragma unroll
    for (int kc = 0; kc < 2; kc++)
      qa[qt][kc] = *(const bf16x8*)(Qt + hb + (size_t)(tq0 + qt) * 1024 +
                                    kc * 512 + lane * 8);

  // stage chunk pair `mc` (chunks 2mc, 2mc+1): 16 KB K + 16 KB V contiguous.
#define STAGE(mc_, buf_)                                                      \
  {                                                                           \
    const size_t pb_ = hb + (size_t)(mc_) * 8192;                             \
    async_copy16(Kt + pb_ + (size_t)t * 8, (char*)&Kst[buf_][0] + w * 1024);  \
    async_copy16(Kt + pb_ + 4096 + (size_t)t * 8,                             \
                 (char*)&Kst[buf_][0] + 8192 + w * 1024);                     \
    async_copy16(Vt + pb_ + (size_t)t * 8, (char*)&Vst[buf_][0] + w * 1024);  \
    async_copy16(Vt + pb_ + 4096 + (size_t)t * 8,                             \
                 (char*)&Vst[buf_][0] + 8192 + w * 1024);                     \
  }

  STAGE(0, 0);

  f32x4 oT[2][4] = {};  // [qt][dkt]
  float ls[2] = {0.f, 0.f};

  // byte offset of this lane's V b64 within a (dkt, kvc) half-tile:
  // picks V[kv = quad*4 + e][dk = dkt*16 + l16], e=0..3.
  const int vb0 = ((quad >> 1) * 16 + l16) * 16 + (quad & 1) * 8;
  const int laneK = lane * 16;

  const int NMC = L / 128;  // 32 macro-iters, one chunk per group each
  for (int mc = 0; mc < NMC; mc++) {
    const int buf = mc & 1;
    __syncthreads();  // drains last macro-iter's copies; protects dbuf WAR
    if (mc + 1 < NMC) STAGE(mc + 1, buf ^ 1);

    const char* Kc = (const char*)&Kst[buf][0] + g * 8192;
    const char* Vc = (const char*)&Vst[buf][0] + g * 8192;

    // QK^T for both q-tiles; K frags read once (b128, conflict-free).
    f32x4 sT[2][4];
#pragma unroll
    for (int tt = 0; tt < 4; tt++) {
      const bf16x8 k0 = *(const bf16x8*)(Kc + tt * 2048 + laneK);
      const bf16x8 k1 = *(const bf16x8*)(Kc + tt * 2048 + 1024 + laneK);
#pragma unroll
      for (int qt = 0; qt < 2; qt++) {
        f32x4 z = {0.f, 0.f, 0.f, 0.f};
        z = MFMA_BF16(k0, qa[qt][0], z, 0, 0, 0);
        z = MFMA_BF16(k1, qa[qt][1], z, 0, 0, 0);
        sT[qt][tt] = z;
      }
    }

    // softmax: p = 2^s, row-sum partials, pack into PV B-frags in-register.
    // packet tt (kv = quad*4+r+16tt) -> pb[qt][tt>>1].v4[tt&1].
    V8 pb[2][2];
#pragma unroll
    for (int qt = 0; qt < 2; qt++) {
#pragma unroll
      for (int tt = 0; tt < 4; tt++) {
        bf16x4 pk;
        float rs = 0.f;
#pragma unroll
        for (int r = 0; r < 4; r++) {
          const float pv = __builtin_amdgcn_exp2f(sT[qt][tt][r]);
          rs += pv;
          pk[r] = (bf16_t)pv;
        }
        ls[qt] += rs;
        pb[qt][tt >> 1].v4[tt & 1] = pk;
      }
    }

    // O^T += V^T . P with k-slots in P's native order: A-frag elem e of
    // lane (quad,l16) must be V[kv = kvc*32 + {quad*4+e, 16+quad*4+e}] ->
    // two b64 reads at +0 / +512 B within the kvc half-tile.
#pragma unroll
    for (int dkt = 0; dkt < 4; dkt++) {
      V8 u0, u1;
      u0.v4[0] = *(const bf16x4*)(Vc + dkt * 2048 + vb0);
      u0.v4[1] = *(const bf16x4*)(Vc + dkt * 2048 + vb0 + 512);
      u1.v4[0] = *(const bf16x4*)(Vc + dkt * 2048 + 1024 + vb0);
      u1.v4[1] = *(const bf16x4*)(Vc + dkt * 2048 + 1024 + vb0 + 512);
#pragma unroll
      for (int qt = 0; qt < 2; qt++) {
        oT[qt][dkt] = MFMA_BF16(u0.v8, pb[qt][0].v8, oT[qt][dkt], 0, 0, 0);
        oT[qt][dkt] = MFMA_BF16(u1.v8, pb[qt][1].v8, oT[qt][dkt], 0, 0, 0);
      }
    }
  }
#undef STAGE

  // cross-group combine: g=1 waves hand partial (oT, ls) to matching g=0
  // wave via LDS scratch (qt0 in Kst, qt1 in Vst; stride 20 floats for
  // 16B-aligned f32x4).  20.5 KB per buffer < 32 KB.
  __syncthreads();
  float* sc0 = (float*)&Kst[0][0];
  float* sc1 = (float*)&Vst[0][0];
  const int sidx = (ws * 64 + lane) * 20;
  if (g == 1) {
#pragma unroll
    for (int dkt = 0; dkt < 4; dkt++) {
      *(f32x4*)(sc0 + sidx + dkt * 4) = oT[0][dkt];
      *(f32x4*)(sc1 + sidx + dkt * 4) = oT[1][dkt];
    }
    sc0[sidx + 16] = ls[0];
    sc1[sidx + 16] = ls[1];
  }
  __syncthreads();
  if (g == 0) {
#pragma unroll
    for (int dkt = 0; dkt < 4; dkt++) {
      oT[0][dkt] += *(const f32x4*)(sc0 + sidx + dkt * 4);
      oT[1][dkt] += *(const f32x4*)(sc1 + sidx + dkt * 4);
    }
    ls[0] += sc0[sidx + 16];
    ls[1] += sc1[sidx + 16];

#pragma unroll
    for (int qt = 0; qt < 2; qt++) {
      float l = ls[qt];
      l += __shfl_xor(l, 16);
      l += __shfl_xor(l, 32);
      const float inv = 1.0f / l;
      const size_t row = (size_t)(tq0 + qt) * 16 + l16;
#pragma unroll
      for (int dkt = 0; dkt < 4; dkt++)
#pragma unroll
        for (int r = 0; r < 4; r++)
          O[row * 1024 + h * 64 + dkt * 16 + quad * 4 + r] =
              (bf16_t)(oT[qt][dkt][r] * inv);
    }
  }
}

// ---------------------------------------------------------------------------
extern "C" void kernel_launch(void* const* d_in, const int* in_sizes, int n_in,
                              void* d_out, int out_size, void* d_ws,
                              size_t ws_size, hipStream_t stream) {
  const float* q  = (const float*)d_in[0];
  const float* k  = (const float*)d_in[1];
  const float* v  = (const float*)d_in[2];
  const float* wq = (const float*)d_in[3];
  const float* bq = (const float*)d_in[4];
  const float* wk = (const float*)d_in[5];
  const float* bk = (const float*)d_in[6];
  const float* wv = (const float*)d_in[7];
  const float* bv = (const float*)d_in[8];
  const float* wo = (const float*)d_in[9];
  const float* bo = (const float*)d_in[10];
  float* out = (float*)d_out;

  const int L = 4096, D = 1024;
  const int nLD = L * D;  // 4M
  const int nDD = D * D;  // 1M
  bf16_t* p = (bf16_t*)d_ws;
  bf16_t* qb  = p; p += nLD;
  bf16_t* kb  = p; p += nLD;
  bf16_t* vb  = p; p += nLD;
  bf16_t* wqb = p; p += nDD;
  bf16_t* wkb = p; p += nDD;
  bf16_t* wvb = p; p += nDD;
  bf16_t* wob = p; p += nDD;
  bf16_t* Qp  = p; p += nLD;
  bf16_t* Kp  = p; p += nLD;
  bf16_t* Vp  = p; p += nLD;
  bf16_t* Qt  = p; p += nLD;
  bf16_t* Kt  = p; p += nLD;
  bf16_t* Vt  = p; p += nLD;
  bf16_t* Op  = Qp;  // reuse: frag_tile consumed Qp before flash writes Op

  dim3 blk(256);
  cast_f32_bf16<<<dim3(nLD / (256 * 8), 1, 7), blk, 0, stream>>>(
      q, qb, nLD, k, kb, nLD, v, vb, nLD, wq, wqb, nDD, wk, wkb, nDD,
      wv, wvb, nDD, wo, wob, nDD);
  gemm3_bt<bf16_t><<<dim3(L / 128, D / 128, 3), blk, 0, stream>>>(
      qb, wqb, bq, Qp, kb, wkb, bk, Kp, vb, wvb, bv, Vp, L, D, D);
  frag_tile<<<dim3(L / 64, 16, 3), blk, 0, stream>>>(Qp, Qt, Kp, Kt, Vp, Vt);
  flash_attn<<<dim3((L / 128) * 16), dim3(512), 0, stream>>>(Qt, Kt, Vt, Op, L);
  gemm3_bt<float><<<dim3(L / 128, D / 128, 1), blk, 0, stream>>>(
      Op, wob, bo, out, Op, wob, bo, out, Op, wob, bo, out, L, D, D);
}